// Round 5
// baseline (574.447 us; speedup 1.0000x reference)
//
#include <hip/hip_runtime.h>
#include <hip/hip_bf16.h>
#include <math.h>

typedef unsigned short u16;
typedef unsigned int   u32;
typedef __bf16  v8bf  __attribute__((ext_vector_type(8)));
typedef float   v4f   __attribute__((ext_vector_type(4)));

#define EPS_H 0.01f

typedef const __attribute__((address_space(1))) void* gas_t;
typedef __attribute__((address_space(3))) void* las_t;
#define GL2LDS(g,l) __builtin_amdgcn_global_load_lds((gas_t)(const void*)(g), (las_t)(void*)(l), 16, 0, 0)

__device__ __forceinline__ u16 f2bf(float f) {
    u32 x = __float_as_uint(f);
    return (u16)((x + 0x7fffu + ((x >> 16) & 1u)) >> 16);   // RNE
}
__device__ __forceinline__ float bfs(u16 v) { return __uint_as_float(((u32)v) << 16); }
__device__ __forceinline__ float selu_f(float x) {
    const float sc = 1.0507009873554805f, al = 1.6732632423543772f;
    return x > 0.f ? sc * x : sc * al * expm1f(x);
}
__device__ __forceinline__ float gelu_f(float x) {
    return 0.5f * x * (1.f + erff(x * 0.7071067811865476f));
}
__device__ __forceinline__ float pe_val(int n, int j) {
    float t = 1000.0f * ((float)(j & ~1) * (1.0f / 512.0f)) + 0.01f;
    float a = (float)n / t;
    return (j & 1) ? cosf(a) : sinf(a);
}

// fragment read from a swizzled [R][32]-bf16 LDS tile (row stride 64B)
__device__ __forceinline__ v8bf lfrag(const u16* base, int row, int lane) {
    int g = (lane >> 4) ^ ((row >> 1) & 3);
    return *(const v8bf*)((const char*)base + row * 64 + g * 16);
}

// ---------------- K0: x fp32 -> bf16 (once)
__global__ __launch_bounds__(256)
void k_xbf(const float* __restrict__ x, u16* __restrict__ xbf)
{
    const size_t i = ((size_t)blockIdx.x * 256 + threadIdx.x) * 8;
    float4 a = *(const float4*)&x[i];
    float4 b = *(const float4*)&x[i + 4];
    ushort4 o0, o1;
    o0.x = f2bf(a.x); o0.y = f2bf(a.y); o0.z = f2bf(a.z); o0.w = f2bf(a.w);
    o1.x = f2bf(b.x); o1.y = f2bf(b.y); o1.z = f2bf(b.z); o1.w = f2bf(b.w);
    *(ushort4*)&xbf[i] = o0;
    *(ushort4*)&xbf[i + 4] = o1;
}

// ---------------- K1: qkv = selu(x @ W + b); q row-major, k/v stored transposed (16-seq chunk)
__global__ __launch_bounds__(256)
void k1_qkv(const u16* __restrict__ xbf, const u16* __restrict__ WT,
            const float* __restrict__ bias, u16* __restrict__ q,
            u16* __restrict__ kT, u16* __restrict__ vT)
{
    __shared__ u16 Als[2][4096];
    __shared__ u16 Bls[2][4096];
    const int tid = threadIdx.x, lane = tid & 63, wave = tid >> 6;
    // XCD-aware bijective swizzle (nwg = 12*128 = 1536, 1536/8 = 192)
    const int orig = blockIdx.x + blockIdx.y * 12;
    const int swz  = (orig & 7) * 192 + (orig >> 3);
    const int col0 = (swz % 12) * 128, row0 = (swz / 12) * 128;
    const int wm = wave >> 1, wn = wave & 1;
    const int ib0 = wave * 2, ib1 = wave * 2 + 1;
    const int rl0 = ib0 * 16 + (lane >> 2), rl1 = ib1 * 16 + (lane >> 2);
    const int gs0 = (lane & 3) ^ ((rl0 >> 1) & 3), gs1 = (lane & 3) ^ ((rl1 >> 1) & 3);
    v4f acc[4][4] = {};

    auto stage = [&](int k0, int b) {
        GL2LDS((const char*)(xbf + (size_t)(row0 + rl0) * 512 + k0) + gs0 * 16, (char*)Als[b] + ib0 * 1024);
        GL2LDS((const char*)(WT  + (size_t)(col0 + rl0) * 512 + k0) + gs0 * 16, (char*)Bls[b] + ib0 * 1024);
        GL2LDS((const char*)(xbf + (size_t)(row0 + rl1) * 512 + k0) + gs1 * 16, (char*)Als[b] + ib1 * 1024);
        GL2LDS((const char*)(WT  + (size_t)(col0 + rl1) * 512 + k0) + gs1 * 16, (char*)Bls[b] + ib1 * 1024);
    };
    auto compute = [&](int b) {
        v8bf av[4], bv2[4];
        #pragma unroll
        for (int f = 0; f < 4; ++f) {
            av[f]  = lfrag(Als[b], wm * 64 + f * 16 + (lane & 15), lane);
            bv2[f] = lfrag(Bls[b], wn * 64 + f * 16 + (lane & 15), lane);
        }
        #pragma unroll
        for (int i2 = 0; i2 < 4; ++i2)
            #pragma unroll
            for (int j2 = 0; j2 < 4; ++j2)
                acc[i2][j2] = __builtin_amdgcn_mfma_f32_16x16x32_bf16(av[i2], bv2[j2], acc[i2][j2], 0, 0, 0);
    };

    stage(0, 0);
    int cur = 0;
    for (int t = 0; t < 15; ++t) {
        __syncthreads();              // prefetched buf[cur] resident (vmcnt drained)
        stage((t + 1) * 32, cur ^ 1); // issue next tile; drains at NEXT barrier
        compute(cur);
        cur ^= 1;
    }
    __syncthreads();
    compute(cur);

    const int region = col0 >> 9;   // 0:q 1:k 2:v (block-uniform)
    #pragma unroll
    for (int fn = 0; fn < 4; ++fn) {
        const int c = col0 + wn * 64 + fn * 16 + (lane & 15);
        const float bc = bias[c];
        #pragma unroll
        for (int fm = 0; fm < 4; ++fm) {
            const int rb = row0 + wm * 64 + fm * 16 + ((lane >> 4) << 2);
            float v0 = selu_f(acc[fm][fn][0] + bc);
            float v1 = selu_f(acc[fm][fn][1] + bc);
            float v2 = selu_f(acc[fm][fn][2] + bc);
            float v3 = selu_f(acc[fm][fn][3] + bc);
            if (region == 0) {
                q[(size_t)(rb + 0) * 512 + c] = f2bf(v0);
                q[(size_t)(rb + 1) * 512 + c] = f2bf(v1);
                q[(size_t)(rb + 2) * 512 + c] = f2bf(v2);
                q[(size_t)(rb + 3) * 512 + c] = f2bf(v3);
            } else {
                ushort4 st; st.x = f2bf(v0); st.y = f2bf(v1); st.z = f2bf(v2); st.w = f2bf(v3);
                const int seq = rb >> 10, n = rb & 1023;
                u16* dst = (region == 1) ? kT : vT;
                const int cc = c - ((region == 1) ? 512 : 1024);
                *(ushort4*)&dst[(size_t)seq * 524288 + (size_t)cc * 1024 + n] = st;
            }
        }
    }
}

// ---------------- K2: Mt[p][d] = (1/512) * sum_m K[m][d] V[m][p]   (per seq, 16-seq chunk)
__global__ __launch_bounds__(256)
void k2_ktv(const u16* __restrict__ kT, const u16* __restrict__ vT, u16* __restrict__ Mt)
{
    __shared__ u16 Als[2][4096];
    __shared__ u16 Bls[2][4096];
    const int tid = threadIdx.x, lane = tid & 63, wave = tid >> 6;
    const int d0 = blockIdx.x * 128, p0 = blockIdx.y * 128, seq = blockIdx.z;
    const u16* Ab = kT + (size_t)seq * 524288;
    const u16* Bb = vT + (size_t)seq * 524288;
    const int wm = wave >> 1, wn = wave & 1;
    const int ib0 = wave * 2, ib1 = wave * 2 + 1;
    const int rl0 = ib0 * 16 + (lane >> 2), rl1 = ib1 * 16 + (lane >> 2);
    const int gs0 = (lane & 3) ^ ((rl0 >> 1) & 3), gs1 = (lane & 3) ^ ((rl1 >> 1) & 3);
    v4f acc[4][4] = {};

    auto stage = [&](int m0, int b) {
        GL2LDS((const char*)(Ab + (size_t)(d0 + rl0) * 1024 + m0) + gs0 * 16, (char*)Als[b] + ib0 * 1024);
        GL2LDS((const char*)(Bb + (size_t)(p0 + rl0) * 1024 + m0) + gs0 * 16, (char*)Bls[b] + ib0 * 1024);
        GL2LDS((const char*)(Ab + (size_t)(d0 + rl1) * 1024 + m0) + gs1 * 16, (char*)Als[b] + ib1 * 1024);
        GL2LDS((const char*)(Bb + (size_t)(p0 + rl1) * 1024 + m0) + gs1 * 16, (char*)Bls[b] + ib1 * 1024);
    };
    auto compute = [&](int b) {
        v8bf av[4], bv[4];
        #pragma unroll
        for (int f = 0; f < 4; ++f) {
            av[f] = lfrag(Als[b], wm * 64 + f * 16 + (lane & 15), lane);
            bv[f] = lfrag(Bls[b], wn * 64 + f * 16 + (lane & 15), lane);
        }
        #pragma unroll
        for (int i2 = 0; i2 < 4; ++i2)
            #pragma unroll
            for (int j2 = 0; j2 < 4; ++j2)
                acc[i2][j2] = __builtin_amdgcn_mfma_f32_16x16x32_bf16(av[i2], bv[j2], acc[i2][j2], 0, 0, 0);
    };

    stage(0, 0);
    int cur = 0;
    for (int t = 0; t < 31; ++t) {
        __syncthreads();
        stage((t + 1) * 32, cur ^ 1);
        compute(cur);
        cur ^= 1;
    }
    __syncthreads();
    compute(cur);

    #pragma unroll
    for (int fn = 0; fn < 4; ++fn) {
        const int p = p0 + wn * 64 + fn * 16 + (lane & 15);
        #pragma unroll
        for (int fm = 0; fm < 4; ++fm) {
            const int d = d0 + wm * 64 + fm * 16 + ((lane >> 4) << 2);
            ushort4 st;
            st.x = f2bf(acc[fm][fn][0] * (1.f / 512.f));
            st.y = f2bf(acc[fm][fn][1] * (1.f / 512.f));
            st.z = f2bf(acc[fm][fn][2] * (1.f / 512.f));
            st.w = f2bf(acc[fm][fn][3] * (1.f / 512.f));
            *(ushort4*)&Mt[(size_t)seq * 262144 + (size_t)p * 512 + d] = st;   // transposed store
        }
    }
}

// ---------------- K3a: S[n][p] = sum_d q[n][d] * Mt[p][d]   (per-seq Mt), S bf16
__global__ __launch_bounds__(256)
void k3a_s(const u16* __restrict__ q, const u16* __restrict__ Mt, u16* __restrict__ S)
{
    __shared__ u16 Als[2][4096];
    __shared__ u16 Bls[2][4096];
    const int tid = threadIdx.x, lane = tid & 63, wave = tid >> 6;
    const int p0 = blockIdx.x * 128, row0 = blockIdx.y * 128;
    const int seq = row0 >> 10;
    const u16* Ab = q + (size_t)row0 * 512;
    const u16* Bb = Mt + (size_t)seq * 262144 + (size_t)p0 * 512;
    const int wm = wave >> 1, wn = wave & 1;
    const int ib0 = wave * 2, ib1 = wave * 2 + 1;
    const int rl0 = ib0 * 16 + (lane >> 2), rl1 = ib1 * 16 + (lane >> 2);
    const int gs0 = (lane & 3) ^ ((rl0 >> 1) & 3), gs1 = (lane & 3) ^ ((rl1 >> 1) & 3);
    v4f acc[4][4] = {};

    auto stage = [&](int k0, int b) {
        GL2LDS((const char*)(Ab + (size_t)rl0 * 512 + k0) + gs0 * 16, (char*)Als[b] + ib0 * 1024);
        GL2LDS((const char*)(Bb + (size_t)rl0 * 512 + k0) + gs0 * 16, (char*)Bls[b] + ib0 * 1024);
        GL2LDS((const char*)(Ab + (size_t)rl1 * 512 + k0) + gs1 * 16, (char*)Als[b] + ib1 * 1024);
        GL2LDS((const char*)(Bb + (size_t)rl1 * 512 + k0) + gs1 * 16, (char*)Bls[b] + ib1 * 1024);
    };
    auto compute = [&](int b) {
        v8bf av[4], bv[4];
        #pragma unroll
        for (int f = 0; f < 4; ++f) {
            av[f] = lfrag(Als[b], wm * 64 + f * 16 + (lane & 15), lane);
            bv[f] = lfrag(Bls[b], wn * 64 + f * 16 + (lane & 15), lane);
        }
        #pragma unroll
        for (int i2 = 0; i2 < 4; ++i2)
            #pragma unroll
            for (int j2 = 0; j2 < 4; ++j2)
                acc[i2][j2] = __builtin_amdgcn_mfma_f32_16x16x32_bf16(av[i2], bv[j2], acc[i2][j2], 0, 0, 0);
    };

    stage(0, 0);
    int cur = 0;
    for (int t = 0; t < 15; ++t) {
        __syncthreads();
        stage((t + 1) * 32, cur ^ 1);
        compute(cur);
        cur ^= 1;
    }
    __syncthreads();
    compute(cur);

    #pragma unroll
    for (int fn = 0; fn < 4; ++fn) {
        const int c = p0 + wn * 64 + fn * 16 + (lane & 15);
        #pragma unroll
        for (int fm = 0; fm < 4; ++fm) {
            const int rb = row0 + wm * 64 + fm * 16 + ((lane >> 4) << 2);
            S[(size_t)(rb + 0) * 512 + c] = f2bf(acc[fm][fn][0]);
            S[(size_t)(rb + 1) * 512 + c] = f2bf(acc[fm][fn][1]);
            S[(size_t)(rb + 2) * 512 + c] = f2bf(acc[fm][fn][2]);
            S[(size_t)(rb + 3) * 512 + c] = f2bf(acc[fm][fn][3]);
        }
    }
}

// ---------------- K3b: in-place row softmax over 512 cols (one wave per row)
__global__ __launch_bounds__(256)
void k3b_sm(u16* __restrict__ S)
{
    const int row  = blockIdx.x * 4 + (threadIdx.x >> 6);
    const int lane = threadIdx.x & 63;
    u16* rp = S + (size_t)row * 512 + lane * 8;
    ushort4 u0 = *(const ushort4*)rp;
    ushort4 u1 = *(const ushort4*)(rp + 4);
    float f[8] = {bfs(u0.x), bfs(u0.y), bfs(u0.z), bfs(u0.w),
                  bfs(u1.x), bfs(u1.y), bfs(u1.z), bfs(u1.w)};
    float m = f[0];
    #pragma unroll
    for (int j = 1; j < 8; ++j) m = fmaxf(m, f[j]);
    #pragma unroll
    for (int off = 32; off > 0; off >>= 1) m = fmaxf(m, __shfl_xor(m, off));
    float s = 0.f;
    #pragma unroll
    for (int j = 0; j < 8; ++j) { f[j] = expf(f[j] - m); s += f[j]; }
    #pragma unroll
    for (int off = 32; off > 0; off >>= 1) s += __shfl_xor(s, off);
    const float inv = 1.0f / s;
    ushort4 o0, o1;
    o0.x = f2bf(f[0] * inv); o0.y = f2bf(f[1] * inv);
    o0.z = f2bf(f[2] * inv); o0.w = f2bf(f[3] * inv);
    o1.x = f2bf(f[4] * inv); o1.y = f2bf(f[5] * inv);
    o1.z = f2bf(f[6] * inv); o1.w = f2bf(f[7] * inv);
    *(ushort4*)rp = o0;
    *(ushort4*)(rp + 4) = o1;
}

// ---------------- K3c: mode 0: out = gelu(att@WpT^T + bp)           (head 0, fp32 store)
//                       mode 1: out = gelu(...) + EPS*out + pe       (head 3, final)
__global__ __launch_bounds__(256)
void k3c_proj(const u16* __restrict__ att, const u16* __restrict__ WpT,
              const float* __restrict__ bp, const float* __restrict__ pe,
              float* __restrict__ out, const int mode, const int rowbase)
{
    __shared__ u16 Als[2][4096];
    __shared__ u16 Bls[2][4096];
    const int tid = threadIdx.x, lane = tid & 63, wave = tid >> 6;
    const int e0 = blockIdx.x * 128, row0 = blockIdx.y * 128;
    const u16* Ab = att + (size_t)row0 * 512;
    const u16* Bb = WpT + (size_t)e0 * 512;
    const int wm = wave >> 1, wn = wave & 1;
    const int ib0 = wave * 2, ib1 = wave * 2 + 1;
    const int rl0 = ib0 * 16 + (lane >> 2), rl1 = ib1 * 16 + (lane >> 2);
    const int gs0 = (lane & 3) ^ ((rl0 >> 1) & 3), gs1 = (lane & 3) ^ ((rl1 >> 1) & 3);
    v4f acc[4][4] = {};

    auto stage = [&](int k0, int b) {
        GL2LDS((const char*)(Ab + (size_t)rl0 * 512 + k0) + gs0 * 16, (char*)Als[b] + ib0 * 1024);
        GL2LDS((const char*)(Bb + (size_t)rl0 * 512 + k0) + gs0 * 16, (char*)Bls[b] + ib0 * 1024);
        GL2LDS((const char*)(Ab + (size_t)rl1 * 512 + k0) + gs1 * 16, (char*)Als[b] + ib1 * 1024);
        GL2LDS((const char*)(Bb + (size_t)rl1 * 512 + k0) + gs1 * 16, (char*)Bls[b] + ib1 * 1024);
    };
    auto compute = [&](int b) {
        v8bf av[4], bv[4];
        #pragma unroll
        for (int f = 0; f < 4; ++f) {
            av[f] = lfrag(Als[b], wm * 64 + f * 16 + (lane & 15), lane);
            bv[f] = lfrag(Bls[b], wn * 64 + f * 16 + (lane & 15), lane);
        }
        #pragma unroll
        for (int i2 = 0; i2 < 4; ++i2)
            #pragma unroll
            for (int j2 = 0; j2 < 4; ++j2)
                acc[i2][j2] = __builtin_amdgcn_mfma_f32_16x16x32_bf16(av[i2], bv[j2], acc[i2][j2], 0, 0, 0);
    };

    stage(0, 0);
    int cur = 0;
    for (int t = 0; t < 15; ++t) {
        __syncthreads();
        stage((t + 1) * 32, cur ^ 1);
        compute(cur);
        cur ^= 1;
    }
    __syncthreads();
    compute(cur);

    #pragma unroll
    for (int fn = 0; fn < 4; ++fn) {
        const int e = e0 + wn * 64 + fn * 16 + (lane & 15);
        const float be = bp[e];
        #pragma unroll
        for (int fm = 0; fm < 4; ++fm) {
            const int rb = row0 + wm * 64 + fm * 16 + ((lane >> 4) << 2);
            #pragma unroll
            for (int j = 0; j < 4; ++j) {
                const int r = rowbase + rb + j;
                const float g = gelu_f(acc[fm][fn][j] + be);
                const size_t o = (size_t)r * 512 + e;
                if (mode == 0) out[o] = g;
                else           out[o] = g + EPS_H * out[o] + pe[(r & 1023) * 512 + e];
            }
        }
    }
}

// ---------------- prep: fp32 [rows][cols] -> bf16 transposed [cols][rows]
__global__ __launch_bounds__(256)
void k_tr(const float* __restrict__ src, u16* __restrict__ dst, int rows, int cols)
{
    __shared__ float t[32][33];
    const int tid = threadIdx.x;
    const int c0 = blockIdx.x * 32, r0 = blockIdx.y * 32;
    #pragma unroll
    for (int i = 0; i < 4; ++i) {
        int idx = tid + i * 256;
        int rr = idx >> 5, cc = idx & 31;
        t[rr][cc] = src[(size_t)(r0 + rr) * cols + c0 + cc];
    }
    __syncthreads();
    #pragma unroll
    for (int i = 0; i < 4; ++i) {
        int idx = tid + i * 256;
        int rr = idx >> 5, cc = idx & 31;
        dst[(size_t)(c0 + rr) * rows + r0 + cc] = f2bf(t[cc][rr]);
    }
}

__global__ __launch_bounds__(256)
void k_pe(float* __restrict__ pe)
{
    int idx = blockIdx.x * 256 + threadIdx.x;
    pe[idx] = pe_val(idx >> 9, idx & 511);
}

extern "C" void kernel_launch(void* const* d_in, const int* in_sizes, int n_in,
                              void* d_out, int out_size, void* d_ws, size_t ws_size,
                              hipStream_t stream)
{
    const float* x    = (const float*)d_in[0];
    const float* Wqkv = (const float*)d_in[1];
    const float* bqkv = (const float*)d_in[2];
    const float* Wp   = (const float*)d_in[3];
    const float* bp   = (const float*)d_in[4];
    float* out = (float*)d_out;

    char* ws = (char*)d_ws;
    u16*   xbf = (u16*)(ws);                      // 32 MiB  [32768][512] bf16
    u16*   q   = (u16*)(ws + 33554432);           // 16 MiB  [16384][512]      (chunk)
    u16*   kT  = (u16*)(ws + 50331648);           // 16 MiB  [16][512][1024]   (chunk; reused as S)
    u16*   vT  = (u16*)(ws + 67108864);           // 16 MiB  [16][512][1024]   (chunk)
    u16*   Mt  = (u16*)(ws + 83886080);           //  8 MiB  [16][512][512]    (chunk)
    u16*   WqT = (u16*)(ws + 92274688);           //  3 MiB  [2][1536][512]
    u16*   WpT = (u16*)(ws + 95420416);           //  1 MiB  [2][512][512]
    float* pe  = (float*)(ws + 96468992);         //  2 MiB  [1024][512]
    u16*   S   = kT;                              // S/att alias (kT dead after K2)

    k_xbf<<<8192, 256, 0, stream>>>(x, xbf);
    k_pe<<<2048, 256, 0, stream>>>(pe);
    for (int hh = 0; hh < 2; ++hh) {
        const int h = hh ? 3 : 0;   // heads 1,2 provably do not affect the output
        k_tr<<<dim3(48, 16), 256, 0, stream>>>(Wqkv + (size_t)h * 786432, WqT + (size_t)hh * 786432, 512, 1536);
        k_tr<<<dim3(16, 16), 256, 0, stream>>>(Wp   + (size_t)h * 262144, WpT + (size_t)hh * 262144, 512, 512);
    }
    for (int p = 0; p < 2; ++p) {
        const int h = p ? 3 : 0;
        for (int ck = 0; ck < 2; ++ck) {
            const u16* xc = xbf + (size_t)ck * 16384 * 512;
            k1_qkv<<<dim3(12, 128), 256, 0, stream>>>(xc, WqT + (size_t)p * 786432,
                                                      bqkv + (size_t)h * 1536, q, kT, vT);
            k2_ktv<<<dim3(4, 4, 16), 256, 0, stream>>>(kT, vT, Mt);
            k3a_s<<<dim3(4, 128), 256, 0, stream>>>(q, Mt, S);
            k3b_sm<<<4096, 256, 0, stream>>>(S);
            k3c_proj<<<dim3(4, 128), 256, 0, stream>>>(S, WpT + (size_t)p * 262144,
                                                       bp + (size_t)h * 512, pe, out, p, ck * 16384);
        }
    }
}

// Round 6
// 541.572 us; speedup vs baseline: 1.0607x; 1.0607x over previous
//
#include <hip/hip_runtime.h>
#include <hip/hip_bf16.h>
#include <math.h>

typedef unsigned short u16;
typedef unsigned int   u32;
typedef __bf16  v8bf  __attribute__((ext_vector_type(8)));
typedef float   v4f   __attribute__((ext_vector_type(4)));

#define EPS_H 0.01f

typedef const __attribute__((address_space(1))) void* gas_t;
typedef __attribute__((address_space(3))) void* las_t;
#define GL2LDS(g,l) __builtin_amdgcn_global_load_lds((gas_t)(const void*)(g), (las_t)(void*)(l), 16, 0, 0)

__device__ __forceinline__ u16 f2bf(float f) {           // native RNE cvt
    __bf16 h = (__bf16)f;
    return *reinterpret_cast<u16*>(&h);
}
__device__ __forceinline__ float bfs(u16 v) { return __uint_as_float(((u32)v) << 16); }
__device__ __forceinline__ float selu_f(float x) {       // fast path: v_exp_f32
    const float sc = 1.0507009873554805f, al = 1.6732632423543772f;
    return x > 0.f ? sc * x : sc * al * (__expf(x) - 1.0f);
}
__device__ __forceinline__ float gelu_f(float x) {
    return 0.5f * x * (1.f + erff(x * 0.7071067811865476f));
}
__device__ __forceinline__ float pe_val(int n, int j) {
    float t = 1000.0f * ((float)(j & ~1) * (1.0f / 512.0f)) + 0.01f;
    float a = (float)n / t;
    return (j & 1) ? cosf(a) : sinf(a);
}

// fragment read from a swizzled [128][32]-bf16 sub-tile (row stride 64B) — R4-proven
__device__ __forceinline__ v8bf lfrag(const u16* base, int row, int lane) {
    int g = (lane >> 4) ^ ((row >> 1) & 3);
    return *(const v8bf*)((const char*)base + row * 64 + g * 16);
}

// stage one 16-KB operand tile (two [128][32] sub-tiles) via global_load_lds,
// pre-swizzled source (R4-proven pattern). g = opbase + tilerow0*gstride + k0.
__device__ __forceinline__ void stage2(const u16* g, size_t gstride, u16* lds, int wave, int lane) {
    const int l2 = lane >> 2;
    #pragma unroll
    for (int i = 0; i < 4; ++i) {
        const int ib  = wave * 4 + i;          // 0..15 chunks of 1024 B
        const int sub = ib >> 3;               // k-half (0: k 0..31, 1: k 32..63)
        const int rl  = (ib & 7) * 16 + l2;    // tile row
        const int gs  = (lane & 3) ^ ((rl >> 1) & 3);
        GL2LDS((const char*)(g + (size_t)rl * gstride + sub * 32) + gs * 16,
               (char*)lds + ib * 1024);
    }
}

__device__ __forceinline__ v8bf packA(const float4& a, const float4& b) {
    v8bf r;
    r[0] = (__bf16)a.x; r[1] = (__bf16)a.y; r[2] = (__bf16)a.z; r[3] = (__bf16)a.w;
    r[4] = (__bf16)b.x; r[5] = (__bf16)b.y; r[6] = (__bf16)b.z; r[7] = (__bf16)b.w;
    return r;
}

#define COMPUTE_TILE(Abuf, Bbuf)                                                   \
    {                                                                              \
        const u16* A0 = &(Abuf)[0];    const u16* A1 = &(Abuf)[4096];              \
        const u16* B0 = &(Bbuf)[0];    const u16* B1 = &(Bbuf)[4096];              \
        v8bf b0[4], b1[4];                                                         \
        _Pragma("unroll")                                                          \
        for (int fc = 0; fc < 4; ++fc) {                                           \
            const int brow = wn * 64 + fc * 16 + (lane & 15);                      \
            b0[fc] = lfrag(B0, brow, lane);                                        \
            b1[fc] = lfrag(B1, brow, lane);                                        \
        }                                                                          \
        __builtin_amdgcn_s_setprio(1);                                             \
        _Pragma("unroll")                                                          \
        for (int fr = 0; fr < 4; ++fr) {                                           \
            const int arow = wm * 64 + fr * 16 + (lane & 15);                      \
            v8bf a0 = lfrag(A0, arow, lane);                                       \
            v8bf a1 = lfrag(A1, arow, lane);                                       \
            _Pragma("unroll")                                                      \
            for (int fc = 0; fc < 4; ++fc) {                                       \
                acc[fr][fc] = __builtin_amdgcn_mfma_f32_16x16x32_bf16(a0, b0[fc], acc[fr][fc], 0, 0, 0); \
                acc[fr][fc] = __builtin_amdgcn_mfma_f32_16x16x32_bf16(a1, b1[fc], acc[fr][fc], 0, 0, 0); \
            }                                                                      \
        }                                                                          \
        __builtin_amdgcn_s_setprio(0);                                             \
    }

// ---------------- K1: qkv = selu(x @ W + b); q row-major, k/v stored transposed (full M)
__global__ __launch_bounds__(256, 1)
void k1_qkv(const float* __restrict__ x, const u16* __restrict__ WT,
            const float* __restrict__ bias, u16* __restrict__ q,
            u16* __restrict__ kT, u16* __restrict__ vT)
{
    __shared__ u16 Als[2][8192];
    __shared__ u16 Bls[2][8192];
    const int tid = threadIdx.x, lane = tid & 63, wave = tid >> 6;
    const int orig = blockIdx.x + blockIdx.y * 12;          // grid (12, 256) = 3072
    const int swz  = (orig & 7) * 384 + (orig >> 3);        // XCD-bijective
    const int col0 = (swz % 12) * 128, row0 = (swz / 12) * 128;
    const int wm = wave >> 1, wn = wave & 1;

    // A reg-staging map: thread covers one 64-B row-half of the A tile
    const int ar = tid & 127, asub = tid >> 7;
    const float* xrow = x + (size_t)(row0 + ar) * 512 + asub * 32;
    const int aswz = (ar >> 1) & 3;

    v4f acc[4][4] = {};
    float4 av[8];

    // prologue: tile 0 -> buf 0
    #pragma unroll
    for (int j = 0; j < 8; ++j) av[j] = *(const float4*)(xrow + j * 4);
    stage2(WT + (size_t)col0 * 512, 512, &Bls[0][0], wave, lane);
    #pragma unroll
    for (int ch = 0; ch < 4; ++ch) {
        const int byteo = asub * 8192 + ar * 64 + ((ch ^ aswz) << 4);
        *(v8bf*)((char*)&Als[0][0] + byteo) = packA(av[2 * ch], av[2 * ch + 1]);
    }

    for (int t = 0; t < 8; ++t) {
        const int c = t & 1;
        __syncthreads();                        // drains buf[c]'s staging (covered by prev tile)
        if (t < 7) {
            const int k0 = (t + 1) * 64;
            #pragma unroll
            for (int j = 0; j < 8; ++j) av[j] = *(const float4*)(xrow + k0 + j * 4);
            stage2(WT + (size_t)col0 * 512 + k0, 512, &Bls[c ^ 1][0], wave, lane);
        }
        COMPUTE_TILE(Als[c], Bls[c]);
        if (t < 7) {
            #pragma unroll
            for (int ch = 0; ch < 4; ++ch) {
                const int byteo = asub * 8192 + ar * 64 + ((ch ^ aswz) << 4);
                *(v8bf*)((char*)&Als[c ^ 1][0] + byteo) = packA(av[2 * ch], av[2 * ch + 1]);
            }
        }
    }

    const int region = col0 >> 9;   // 0:q 1:k 2:v (block-uniform; 128 | 512)
    #pragma unroll
    for (int fn = 0; fn < 4; ++fn) {
        const int c = col0 + wn * 64 + fn * 16 + (lane & 15);
        const float bc = bias[c];
        #pragma unroll
        for (int fm = 0; fm < 4; ++fm) {
            const int rb = row0 + wm * 64 + fm * 16 + ((lane >> 4) << 2);
            float v0 = selu_f(acc[fm][fn][0] + bc);
            float v1 = selu_f(acc[fm][fn][1] + bc);
            float v2 = selu_f(acc[fm][fn][2] + bc);
            float v3 = selu_f(acc[fm][fn][3] + bc);
            if (region == 0) {
                q[(size_t)(rb + 0) * 512 + c] = f2bf(v0);
                q[(size_t)(rb + 1) * 512 + c] = f2bf(v1);
                q[(size_t)(rb + 2) * 512 + c] = f2bf(v2);
                q[(size_t)(rb + 3) * 512 + c] = f2bf(v3);
            } else {
                ushort4 st; st.x = f2bf(v0); st.y = f2bf(v1); st.z = f2bf(v2); st.w = f2bf(v3);
                const int seq = rb >> 10, n = rb & 1023;
                u16* dst = (region == 1) ? kT : vT;
                const int cc = c - ((region == 1) ? 512 : 1024);
                *(ushort4*)&dst[(size_t)seq * 524288 + (size_t)cc * 1024 + n] = st;
            }
        }
    }
}

// ---------------- K2: Mt[p][d] = (1/512) * sum_m K[m][d] V[m][p]   (per seq, full)
__global__ __launch_bounds__(256, 1)
void k2_ktv(const u16* __restrict__ kT, const u16* __restrict__ vT, u16* __restrict__ Mt)
{
    __shared__ u16 Als[2][8192];
    __shared__ u16 Bls[2][8192];
    const int tid = threadIdx.x, lane = tid & 63, wave = tid >> 6;
    const int d0 = blockIdx.x * 128, p0 = blockIdx.y * 128, seq = blockIdx.z;
    const u16* Ab = kT + (size_t)seq * 524288 + (size_t)d0 * 1024;
    const u16* Bb = vT + (size_t)seq * 524288 + (size_t)p0 * 1024;
    const int wm = wave >> 1, wn = wave & 1;
    v4f acc[4][4] = {};

    stage2(Ab, 1024, &Als[0][0], wave, lane);
    stage2(Bb, 1024, &Bls[0][0], wave, lane);
    for (int t = 0; t < 16; ++t) {
        const int c = t & 1;
        __syncthreads();
        if (t < 15) {
            const int m0 = (t + 1) * 64;
            stage2(Ab + m0, 1024, &Als[c ^ 1][0], wave, lane);
            stage2(Bb + m0, 1024, &Bls[c ^ 1][0], wave, lane);
        }
        COMPUTE_TILE(Als[c], Bls[c]);
    }

    #pragma unroll
    for (int fn = 0; fn < 4; ++fn) {
        const int p = p0 + wn * 64 + fn * 16 + (lane & 15);
        #pragma unroll
        for (int fm = 0; fm < 4; ++fm) {
            const int d = d0 + wm * 64 + fm * 16 + ((lane >> 4) << 2);
            ushort4 st;
            st.x = f2bf(acc[fm][fn][0] * (1.f / 512.f));
            st.y = f2bf(acc[fm][fn][1] * (1.f / 512.f));
            st.z = f2bf(acc[fm][fn][2] * (1.f / 512.f));
            st.w = f2bf(acc[fm][fn][3] * (1.f / 512.f));
            *(ushort4*)&Mt[(size_t)seq * 262144 + (size_t)p * 512 + d] = st;
        }
    }
}

// ---------------- K3a: S[n][p] = sum_d q[n][d] * Mt[p][d]   (S bf16, full M)
__global__ __launch_bounds__(256, 1)
void k3a_s(const u16* __restrict__ q, const u16* __restrict__ Mt, u16* __restrict__ S)
{
    __shared__ u16 Als[2][8192];
    __shared__ u16 Bls[2][8192];
    const int tid = threadIdx.x, lane = tid & 63, wave = tid >> 6;
    const int orig = blockIdx.x + blockIdx.y * 4;           // grid (4, 256) = 1024
    const int swz  = (orig & 7) * 128 + (orig >> 3);
    const int p0 = (swz % 4) * 128, row0 = (swz / 4) * 128;
    const int seq = row0 >> 10;
    const u16* Ab = q + (size_t)row0 * 512;
    const u16* Bb = Mt + (size_t)seq * 262144 + (size_t)p0 * 512;
    const int wm = wave >> 1, wn = wave & 1;
    v4f acc[4][4] = {};

    stage2(Ab, 512, &Als[0][0], wave, lane);
    stage2(Bb, 512, &Bls[0][0], wave, lane);
    for (int t = 0; t < 8; ++t) {
        const int c = t & 1;
        __syncthreads();
        if (t < 7) {
            const int k0 = (t + 1) * 64;
            stage2(Ab + k0, 512, &Als[c ^ 1][0], wave, lane);
            stage2(Bb + k0, 512, &Bls[c ^ 1][0], wave, lane);
        }
        COMPUTE_TILE(Als[c], Bls[c]);
    }

    #pragma unroll
    for (int fn = 0; fn < 4; ++fn) {
        const int c = p0 + wn * 64 + fn * 16 + (lane & 15);
        #pragma unroll
        for (int fm = 0; fm < 4; ++fm) {
            const int rb = row0 + wm * 64 + fm * 16 + ((lane >> 4) << 2);
            S[(size_t)(rb + 0) * 512 + c] = f2bf(acc[fm][fn][0]);
            S[(size_t)(rb + 1) * 512 + c] = f2bf(acc[fm][fn][1]);
            S[(size_t)(rb + 2) * 512 + c] = f2bf(acc[fm][fn][2]);
            S[(size_t)(rb + 3) * 512 + c] = f2bf(acc[fm][fn][3]);
        }
    }
}

// ---------------- K3b: in-place row softmax over 512 cols (one wave per row)
__global__ __launch_bounds__(256)
void k3b_sm(u16* __restrict__ S)
{
    const int row  = blockIdx.x * 4 + (threadIdx.x >> 6);
    const int lane = threadIdx.x & 63;
    u16* rp = S + (size_t)row * 512 + lane * 8;
    ushort4 u0 = *(const ushort4*)rp;
    ushort4 u1 = *(const ushort4*)(rp + 4);
    float f[8] = {bfs(u0.x), bfs(u0.y), bfs(u0.z), bfs(u0.w),
                  bfs(u1.x), bfs(u1.y), bfs(u1.z), bfs(u1.w)};
    float m = f[0];
    #pragma unroll
    for (int j = 1; j < 8; ++j) m = fmaxf(m, f[j]);
    #pragma unroll
    for (int off = 32; off > 0; off >>= 1) m = fmaxf(m, __shfl_xor(m, off));
    float s = 0.f;
    #pragma unroll
    for (int j = 0; j < 8; ++j) { f[j] = __expf(f[j] - m); s += f[j]; }
    #pragma unroll
    for (int off = 32; off > 0; off >>= 1) s += __shfl_xor(s, off);
    const float inv = 1.0f / s;
    ushort4 o0, o1;
    o0.x = f2bf(f[0] * inv); o0.y = f2bf(f[1] * inv);
    o0.z = f2bf(f[2] * inv); o0.w = f2bf(f[3] * inv);
    o1.x = f2bf(f[4] * inv); o1.y = f2bf(f[5] * inv);
    o1.z = f2bf(f[6] * inv); o1.w = f2bf(f[7] * inv);
    *(ushort4*)rp = o0;
    *(ushort4*)(rp + 4) = o1;
}

// ---------------- K3c: mode 0: out = gelu(att@WpT^T + bp)      (head 0)
//                       mode 1: out = gelu(...) + EPS*out + pe  (head 3, final)
__global__ __launch_bounds__(256, 1)
void k3c_proj(const u16* __restrict__ att, const u16* __restrict__ WpT,
              const float* __restrict__ bp, const float* __restrict__ pe,
              float* __restrict__ out, const int mode)
{
    __shared__ u16 Als[2][8192];
    __shared__ u16 Bls[2][8192];
    const int tid = threadIdx.x, lane = tid & 63, wave = tid >> 6;
    const int orig = blockIdx.x + blockIdx.y * 4;           // grid (4, 256) = 1024
    const int swz  = (orig & 7) * 128 + (orig >> 3);
    const int e0 = (swz % 4) * 128, row0 = (swz / 4) * 128;
    const u16* Ab = att + (size_t)row0 * 512;
    const u16* Bb = WpT + (size_t)e0 * 512;
    const int wm = wave >> 1, wn = wave & 1;
    v4f acc[4][4] = {};

    stage2(Ab, 512, &Als[0][0], wave, lane);
    stage2(Bb, 512, &Bls[0][0], wave, lane);
    for (int t = 0; t < 8; ++t) {
        const int c = t & 1;
        __syncthreads();
        if (t < 7) {
            const int k0 = (t + 1) * 64;
            stage2(Ab + k0, 512, &Als[c ^ 1][0], wave, lane);
            stage2(Bb + k0, 512, &Bls[c ^ 1][0], wave, lane);
        }
        COMPUTE_TILE(Als[c], Bls[c]);
    }

    #pragma unroll
    for (int fn = 0; fn < 4; ++fn) {
        const int e = e0 + wn * 64 + fn * 16 + (lane & 15);
        const float be = bp[e];
        #pragma unroll
        for (int fm = 0; fm < 4; ++fm) {
            const int rb = row0 + wm * 64 + fm * 16 + ((lane >> 4) << 2);
            #pragma unroll
            for (int j = 0; j < 4; ++j) {
                const int r = rb + j;
                const float g = gelu_f(acc[fm][fn][j] + be);
                const size_t o = (size_t)r * 512 + e;
                if (mode == 0) out[o] = g;
                else           out[o] = g + EPS_H * out[o] + pe[(r & 1023) * 512 + e];
            }
        }
    }
}

// ---------------- prep: fp32 [rows][cols] -> bf16 transposed [cols][rows]
__global__ __launch_bounds__(256)
void k_tr(const float* __restrict__ src, u16* __restrict__ dst, int rows, int cols)
{
    __shared__ float t[32][33];
    const int tid = threadIdx.x;
    const int c0 = blockIdx.x * 32, r0 = blockIdx.y * 32;
    #pragma unroll
    for (int i = 0; i < 4; ++i) {
        int idx = tid + i * 256;
        int rr = idx >> 5, cc = idx & 31;
        t[rr][cc] = src[(size_t)(r0 + rr) * cols + c0 + cc];
    }
    __syncthreads();
    #pragma unroll
    for (int i = 0; i < 4; ++i) {
        int idx = tid + i * 256;
        int rr = idx >> 5, cc = idx & 31;
        dst[(size_t)(c0 + rr) * rows + r0 + cc] = f2bf(t[cc][rr]);
    }
}

__global__ __launch_bounds__(256)
void k_pe(float* __restrict__ pe)
{
    int idx = blockIdx.x * 256 + threadIdx.x;
    pe[idx] = pe_val(idx >> 9, idx & 511);
}

extern "C" void kernel_launch(void* const* d_in, const int* in_sizes, int n_in,
                              void* d_out, int out_size, void* d_ws, size_t ws_size,
                              hipStream_t stream)
{
    const float* x    = (const float*)d_in[0];
    const float* Wqkv = (const float*)d_in[1];
    const float* bqkv = (const float*)d_in[2];
    const float* Wp   = (const float*)d_in[3];
    const float* bp   = (const float*)d_in[4];
    float* out = (float*)d_out;

    char* ws = (char*)d_ws;                       // 118 MiB total (<= R2-proven 123.7 MiB)
    u16*   q   = (u16*)(ws);                      // 32 MiB  [32768][512]
    u16*   kT  = (u16*)(ws + 33554432);           // 32 MiB  [32][512][1024]; S alias after k2
    u16*   vT  = (u16*)(ws + 67108864);           // 32 MiB  [32][512][1024]
    u16*   Mt  = (u16*)(ws + 100663296);          // 16 MiB  [32][512][512]
    u16*   WqT = (u16*)(ws + 117440512);          //  3 MiB  [2][1536][512]
    u16*   WpT = (u16*)(ws + 120586240);          //  1 MiB  [2][512][512]
    float* pe  = (float*)(ws + 121634816);        //  2 MiB  [1024][512]
    u16*   S   = kT;                              // S/att alias (kT dead after K2)

    k_pe<<<2048, 256, 0, stream>>>(pe);
    for (int hh = 0; hh < 2; ++hh) {
        const int h = hh ? 3 : 0;   // heads 1,2 provably do not affect the output
        k_tr<<<dim3(48, 16), 256, 0, stream>>>(Wqkv + (size_t)h * 786432, WqT + (size_t)hh * 786432, 512, 1536);
        k_tr<<<dim3(16, 16), 256, 0, stream>>>(Wp   + (size_t)h * 262144, WpT + (size_t)hh * 262144, 512, 512);
    }
    for (int p = 0; p < 2; ++p) {
        const int h = p ? 3 : 0;
        k1_qkv<<<dim3(12, 256), 256, 0, stream>>>(x, WqT + (size_t)p * 786432,
                                                  bqkv + (size_t)h * 1536, q, kT, vT);
        k2_ktv<<<dim3(4, 4, 32), 256, 0, stream>>>(kT, vT, Mt);
        k3a_s<<<dim3(4, 256), 256, 0, stream>>>(q, Mt, S);
        k3b_sm<<<8192, 256, 0, stream>>>(S);
        k3c_proj<<<dim3(4, 256), 256, 0, stream>>>(S, WpT + (size_t)p * 262144,
                                                   bp + (size_t)h * 512, pe, out, p);
    }
}

// Round 7
// 459.385 us; speedup vs baseline: 1.2505x; 1.1789x over previous
//
#include <hip/hip_runtime.h>
#include <hip/hip_bf16.h>
#include <math.h>

typedef unsigned short u16;
typedef unsigned int   u32;
typedef __bf16  v8bf  __attribute__((ext_vector_type(8)));
typedef float   v4f   __attribute__((ext_vector_type(4)));

#define EPS_H 0.01f

typedef const __attribute__((address_space(1))) void* gas_t;
typedef __attribute__((address_space(3))) void* las_t;
#define GL2LDS(g,l) __builtin_amdgcn_global_load_lds((gas_t)(const void*)(g), (las_t)(void*)(l), 16, 0, 0)

__device__ __forceinline__ u16 f2bf(float f) {           // native RNE cvt
    __bf16 h = (__bf16)f;
    return *reinterpret_cast<u16*>(&h);
}
__device__ __forceinline__ float bfs(u16 v) { return __uint_as_float(((u32)v) << 16); }
__device__ __forceinline__ float selu_f(float x) {       // fast path: v_exp_f32
    const float sc = 1.0507009873554805f, al = 1.6732632423543772f;
    return x > 0.f ? sc * x : sc * al * (__expf(x) - 1.0f);
}
__device__ __forceinline__ float gelu_f(float x) {
    return 0.5f * x * (1.f + erff(x * 0.7071067811865476f));
}
__device__ __forceinline__ float pe_val(int n, int j) {
    float t = 1000.0f * ((float)(j & ~1) * (1.0f / 512.0f)) + 0.01f;
    float a = (float)n / t;
    return (j & 1) ? cosf(a) : sinf(a);
}

// fragment read from a swizzled [128][32]-bf16 sub-tile (row stride 64B) — R4-proven
__device__ __forceinline__ v8bf lfrag(const u16* base, int row, int lane) {
    int g = (lane >> 4) ^ ((row >> 1) & 3);
    return *(const v8bf*)((const char*)base + row * 64 + g * 16);
}

// stage one 16-KB operand tile (two [128][32] sub-tiles) via global_load_lds,
// pre-swizzled source (R4-proven pattern). g = opbase + tilerow0*gstride + k0.
__device__ __forceinline__ void stage2(const u16* g, size_t gstride, u16* lds, int wave, int lane) {
    const int l2 = lane >> 2;
    #pragma unroll
    for (int i = 0; i < 4; ++i) {
        const int ib  = wave * 4 + i;          // 0..15 chunks of 1024 B
        const int sub = ib >> 3;               // k-half (0: k 0..31, 1: k 32..63)
        const int rl  = (ib & 7) * 16 + l2;    // tile row
        const int gs  = (lane & 3) ^ ((rl >> 1) & 3);
        GL2LDS((const char*)(g + (size_t)rl * gstride + sub * 32) + gs * 16,
               (char*)lds + ib * 1024);
    }
}

#define COMPUTE_TILE(Abuf, Bbuf)                                                   \
    {                                                                              \
        const u16* A0 = &(Abuf)[0];    const u16* A1 = &(Abuf)[4096];              \
        const u16* B0 = &(Bbuf)[0];    const u16* B1 = &(Bbuf)[4096];              \
        v8bf b0[4], b1[4];                                                         \
        _Pragma("unroll")                                                          \
        for (int fc = 0; fc < 4; ++fc) {                                           \
            const int brow = wn * 64 + fc * 16 + (lane & 15);                      \
            b0[fc] = lfrag(B0, brow, lane);                                        \
            b1[fc] = lfrag(B1, brow, lane);                                        \
        }                                                                          \
        __builtin_amdgcn_s_setprio(1);                                             \
        _Pragma("unroll")                                                          \
        for (int fr = 0; fr < 4; ++fr) {                                           \
            const int arow = wm * 64 + fr * 16 + (lane & 15);                      \
            v8bf a0 = lfrag(A0, arow, lane);                                       \
            v8bf a1 = lfrag(A1, arow, lane);                                       \
            _Pragma("unroll")                                                      \
            for (int fc = 0; fc < 4; ++fc) {                                       \
                acc[fr][fc] = __builtin_amdgcn_mfma_f32_16x16x32_bf16(a0, b0[fc], acc[fr][fc], 0, 0, 0); \
                acc[fr][fc] = __builtin_amdgcn_mfma_f32_16x16x32_bf16(a1, b1[fc], acc[fr][fc], 0, 0, 0); \
            }                                                                      \
        }                                                                          \
        __builtin_amdgcn_s_setprio(0);                                             \
    }

// ---------------- K0: x fp32 -> bf16 (once)
__global__ __launch_bounds__(256)
void k_xbf(const float* __restrict__ x, u16* __restrict__ xbf)
{
    const size_t i = ((size_t)blockIdx.x * 256 + threadIdx.x) * 8;
    float4 a = *(const float4*)&x[i];
    float4 b = *(const float4*)&x[i + 4];
    ushort4 o0, o1;
    o0.x = f2bf(a.x); o0.y = f2bf(a.y); o0.z = f2bf(a.z); o0.w = f2bf(a.w);
    o1.x = f2bf(b.x); o1.y = f2bf(b.y); o1.z = f2bf(b.z); o1.w = f2bf(b.w);
    *(ushort4*)&xbf[i] = o0;
    *(ushort4*)&xbf[i + 4] = o1;
}

// ---------------- K1: qkv = selu(x @ W + b); q row-major, k/v transposed (16-seq chunk)
__global__ __launch_bounds__(256, 1)
void k1_qkv(const u16* __restrict__ xbf, const u16* __restrict__ WT,
            const float* __restrict__ bias, u16* __restrict__ q,
            u16* __restrict__ kT, u16* __restrict__ vT)
{
    __shared__ u16 Als[2][8192];
    __shared__ u16 Bls[2][8192];
    const int tid = threadIdx.x, lane = tid & 63, wave = tid >> 6;
    const int orig = blockIdx.x + blockIdx.y * 12;          // grid (12, 128) = 1536
    const int swz  = (orig & 7) * 192 + (orig >> 3);        // XCD-bijective
    const int col0 = (swz % 12) * 128, row0 = (swz / 12) * 128;
    const int wm = wave >> 1, wn = wave & 1;
    const u16* Ab = xbf + (size_t)row0 * 512;
    const u16* Bb = WT + (size_t)col0 * 512;
    v4f acc[4][4] = {};

    stage2(Ab, 512, &Als[0][0], wave, lane);
    stage2(Bb, 512, &Bls[0][0], wave, lane);
    for (int t = 0; t < 8; ++t) {
        const int c = t & 1;
        __syncthreads();                        // prefetched buf[c] resident
        if (t < 7) {
            const int k0 = (t + 1) * 64;
            stage2(Ab + k0, 512, &Als[c ^ 1][0], wave, lane);
            stage2(Bb + k0, 512, &Bls[c ^ 1][0], wave, lane);
        }
        COMPUTE_TILE(Als[c], Bls[c]);
    }

    const int region = col0 >> 9;   // 0:q 1:k 2:v (block-uniform; 128 | 512)
    #pragma unroll
    for (int fn = 0; fn < 4; ++fn) {
        const int c = col0 + wn * 64 + fn * 16 + (lane & 15);
        const float bc = bias[c];
        #pragma unroll
        for (int fm = 0; fm < 4; ++fm) {
            const int rb = row0 + wm * 64 + fm * 16 + ((lane >> 4) << 2);
            float v0 = selu_f(acc[fm][fn][0] + bc);
            float v1 = selu_f(acc[fm][fn][1] + bc);
            float v2 = selu_f(acc[fm][fn][2] + bc);
            float v3 = selu_f(acc[fm][fn][3] + bc);
            if (region == 0) {
                q[(size_t)(rb + 0) * 512 + c] = f2bf(v0);
                q[(size_t)(rb + 1) * 512 + c] = f2bf(v1);
                q[(size_t)(rb + 2) * 512 + c] = f2bf(v2);
                q[(size_t)(rb + 3) * 512 + c] = f2bf(v3);
            } else {
                ushort4 st; st.x = f2bf(v0); st.y = f2bf(v1); st.z = f2bf(v2); st.w = f2bf(v3);
                const int seq = rb >> 10, n = rb & 1023;    // chunk-local
                u16* dst = (region == 1) ? kT : vT;
                const int cc = c - ((region == 1) ? 512 : 1024);
                *(ushort4*)&dst[(size_t)seq * 524288 + (size_t)cc * 1024 + n] = st;
            }
        }
    }
}

// ---------------- K2: Mt[p][d] = (1/512) * sum_m K[m][d] V[m][p]   (per seq, chunk)
__global__ __launch_bounds__(256, 1)
void k2_ktv(const u16* __restrict__ kT, const u16* __restrict__ vT, u16* __restrict__ Mt)
{
    __shared__ u16 Als[2][8192];
    __shared__ u16 Bls[2][8192];
    const int tid = threadIdx.x, lane = tid & 63, wave = tid >> 6;
    const int d0 = blockIdx.x * 128, p0 = blockIdx.y * 128, seq = blockIdx.z;
    const u16* Ab = kT + (size_t)seq * 524288 + (size_t)d0 * 1024;
    const u16* Bb = vT + (size_t)seq * 524288 + (size_t)p0 * 1024;
    const int wm = wave >> 1, wn = wave & 1;
    v4f acc[4][4] = {};

    stage2(Ab, 1024, &Als[0][0], wave, lane);
    stage2(Bb, 1024, &Bls[0][0], wave, lane);
    for (int t = 0; t < 16; ++t) {
        const int c = t & 1;
        __syncthreads();
        if (t < 15) {
            const int m0 = (t + 1) * 64;
            stage2(Ab + m0, 1024, &Als[c ^ 1][0], wave, lane);
            stage2(Bb + m0, 1024, &Bls[c ^ 1][0], wave, lane);
        }
        COMPUTE_TILE(Als[c], Bls[c]);
    }

    #pragma unroll
    for (int fn = 0; fn < 4; ++fn) {
        const int p = p0 + wn * 64 + fn * 16 + (lane & 15);
        #pragma unroll
        for (int fm = 0; fm < 4; ++fm) {
            const int d = d0 + wm * 64 + fm * 16 + ((lane >> 4) << 2);
            ushort4 st;
            st.x = f2bf(acc[fm][fn][0] * (1.f / 512.f));
            st.y = f2bf(acc[fm][fn][1] * (1.f / 512.f));
            st.z = f2bf(acc[fm][fn][2] * (1.f / 512.f));
            st.w = f2bf(acc[fm][fn][3] * (1.f / 512.f));
            *(ushort4*)&Mt[(size_t)seq * 262144 + (size_t)p * 512 + d] = st;
        }
    }
}

// ---------------- K3a: S[n][p] = sum_d q[n][d] * Mt[p][d]   (S bf16, chunk)
__global__ __launch_bounds__(256, 1)
void k3a_s(const u16* __restrict__ q, const u16* __restrict__ Mt, u16* __restrict__ S)
{
    __shared__ u16 Als[2][8192];
    __shared__ u16 Bls[2][8192];
    const int tid = threadIdx.x, lane = tid & 63, wave = tid >> 6;
    const int orig = blockIdx.x + blockIdx.y * 4;           // grid (4, 128) = 512
    const int swz  = (orig & 7) * 64 + (orig >> 3);         // XCD-bijective
    const int p0 = (swz % 4) * 128, row0 = (swz / 4) * 128;
    const int seq = row0 >> 10;                              // chunk-local
    const u16* Ab = q + (size_t)row0 * 512;
    const u16* Bb = Mt + (size_t)seq * 262144 + (size_t)p0 * 512;
    const int wm = wave >> 1, wn = wave & 1;
    v4f acc[4][4] = {};

    stage2(Ab, 512, &Als[0][0], wave, lane);
    stage2(Bb, 512, &Bls[0][0], wave, lane);
    for (int t = 0; t < 8; ++t) {
        const int c = t & 1;
        __syncthreads();
        if (t < 7) {
            const int k0 = (t + 1) * 64;
            stage2(Ab + k0, 512, &Als[c ^ 1][0], wave, lane);
            stage2(Bb + k0, 512, &Bls[c ^ 1][0], wave, lane);
        }
        COMPUTE_TILE(Als[c], Bls[c]);
    }

    #pragma unroll
    for (int fn = 0; fn < 4; ++fn) {
        const int c = p0 + wn * 64 + fn * 16 + (lane & 15);
        #pragma unroll
        for (int fm = 0; fm < 4; ++fm) {
            const int rb = row0 + wm * 64 + fm * 16 + ((lane >> 4) << 2);
            S[(size_t)(rb + 0) * 512 + c] = f2bf(acc[fm][fn][0]);
            S[(size_t)(rb + 1) * 512 + c] = f2bf(acc[fm][fn][1]);
            S[(size_t)(rb + 2) * 512 + c] = f2bf(acc[fm][fn][2]);
            S[(size_t)(rb + 3) * 512 + c] = f2bf(acc[fm][fn][3]);
        }
    }
}

// ---------------- K3b: in-place row softmax over 512 cols (one wave per row)
__global__ __launch_bounds__(256)
void k3b_sm(u16* __restrict__ S)
{
    const int row  = blockIdx.x * 4 + (threadIdx.x >> 6);
    const int lane = threadIdx.x & 63;
    u16* rp = S + (size_t)row * 512 + lane * 8;
    ushort4 u0 = *(const ushort4*)rp;
    ushort4 u1 = *(const ushort4*)(rp + 4);
    float f[8] = {bfs(u0.x), bfs(u0.y), bfs(u0.z), bfs(u0.w),
                  bfs(u1.x), bfs(u1.y), bfs(u1.z), bfs(u1.w)};
    float m = f[0];
    #pragma unroll
    for (int j = 1; j < 8; ++j) m = fmaxf(m, f[j]);
    #pragma unroll
    for (int off = 32; off > 0; off >>= 1) m = fmaxf(m, __shfl_xor(m, off));
    float s = 0.f;
    #pragma unroll
    for (int j = 0; j < 8; ++j) { f[j] = __expf(f[j] - m); s += f[j]; }
    #pragma unroll
    for (int off = 32; off > 0; off >>= 1) s += __shfl_xor(s, off);
    const float inv = 1.0f / s;
    ushort4 o0, o1;
    o0.x = f2bf(f[0] * inv); o0.y = f2bf(f[1] * inv);
    o0.z = f2bf(f[2] * inv); o0.w = f2bf(f[3] * inv);
    o1.x = f2bf(f[4] * inv); o1.y = f2bf(f[5] * inv);
    o1.z = f2bf(f[6] * inv); o1.w = f2bf(f[7] * inv);
    *(ushort4*)rp = o0;
    *(ushort4*)(rp + 4) = o1;
}

// ---------------- K3c: mode 0: out = gelu(att@WpT^T + bp)      (head 0)
//                       mode 1: out = gelu(...) + EPS*out + pe  (head 3, final)
__global__ __launch_bounds__(256, 1)
void k3c_proj(const u16* __restrict__ att, const u16* __restrict__ WpT,
              const float* __restrict__ bp, const float* __restrict__ pe,
              float* __restrict__ out, const int mode, const int rowbase)
{
    __shared__ u16 Als[2][8192];
    __shared__ u16 Bls[2][8192];
    const int tid = threadIdx.x, lane = tid & 63, wave = tid >> 6;
    const int orig = blockIdx.x + blockIdx.y * 4;           // grid (4, 128) = 512
    const int swz  = (orig & 7) * 64 + (orig >> 3);
    const int e0 = (swz % 4) * 128, row0 = (swz / 4) * 128;
    const u16* Ab = att + (size_t)row0 * 512;
    const u16* Bb = WpT + (size_t)e0 * 512;
    const int wm = wave >> 1, wn = wave & 1;
    v4f acc[4][4] = {};

    stage2(Ab, 512, &Als[0][0], wave, lane);
    stage2(Bb, 512, &Bls[0][0], wave, lane);
    for (int t = 0; t < 8; ++t) {
        const int c = t & 1;
        __syncthreads();
        if (t < 7) {
            const int k0 = (t + 1) * 64;
            stage2(Ab + k0, 512, &Als[c ^ 1][0], wave, lane);
            stage2(Bb + k0, 512, &Bls[c ^ 1][0], wave, lane);
        }
        COMPUTE_TILE(Als[c], Bls[c]);
    }

    #pragma unroll
    for (int fn = 0; fn < 4; ++fn) {
        const int e = e0 + wn * 64 + fn * 16 + (lane & 15);
        const float be = bp[e];
        #pragma unroll
        for (int fm = 0; fm < 4; ++fm) {
            const int rb = row0 + wm * 64 + fm * 16 + ((lane >> 4) << 2);
            #pragma unroll
            for (int j = 0; j < 4; ++j) {
                const int r = rowbase + rb + j;
                const float g = gelu_f(acc[fm][fn][j] + be);
                const size_t o = (size_t)r * 512 + e;
                if (mode == 0) out[o] = g;
                else           out[o] = g + EPS_H * out[o] + pe[(r & 1023) * 512 + e];
            }
        }
    }
}

// ---------------- prep: fp32 [rows][cols] -> bf16 transposed [cols][rows]
__global__ __launch_bounds__(256)
void k_tr(const float* __restrict__ src, u16* __restrict__ dst, int rows, int cols)
{
    __shared__ float t[32][33];
    const int tid = threadIdx.x;
    const int c0 = blockIdx.x * 32, r0 = blockIdx.y * 32;
    #pragma unroll
    for (int i = 0; i < 4; ++i) {
        int idx = tid + i * 256;
        int rr = idx >> 5, cc = idx & 31;
        t[rr][cc] = src[(size_t)(r0 + rr) * cols + c0 + cc];
    }
    __syncthreads();
    #pragma unroll
    for (int i = 0; i < 4; ++i) {
        int idx = tid + i * 256;
        int rr = idx >> 5, cc = idx & 31;
        dst[(size_t)(c0 + rr) * rows + r0 + cc] = f2bf(t[cc][rr]);
    }
}

__global__ __launch_bounds__(256)
void k_pe(float* __restrict__ pe)
{
    int idx = blockIdx.x * 256 + threadIdx.x;
    pe[idx] = pe_val(idx >> 9, idx & 511);
}

extern "C" void kernel_launch(void* const* d_in, const int* in_sizes, int n_in,
                              void* d_out, int out_size, void* d_ws, size_t ws_size,
                              hipStream_t stream)
{
    const float* x    = (const float*)d_in[0];
    const float* Wqkv = (const float*)d_in[1];
    const float* bqkv = (const float*)d_in[2];
    const float* Wp   = (const float*)d_in[3];
    const float* bp   = (const float*)d_in[4];
    float* out = (float*)d_out;

    char* ws = (char*)d_ws;                       // 94 MiB total (R4-proven layout)
    u16*   xbf = (u16*)(ws);                      // 32 MiB  [32768][512] bf16
    u16*   q   = (u16*)(ws + 33554432);           // 16 MiB  [16384][512]      (chunk)
    u16*   kT  = (u16*)(ws + 50331648);           // 16 MiB  [16][512][1024]   (chunk; S alias)
    u16*   vT  = (u16*)(ws + 67108864);           // 16 MiB  [16][512][1024]   (chunk)
    u16*   Mt  = (u16*)(ws + 83886080);           //  8 MiB  [16][512][512]    (chunk)
    u16*   WqT = (u16*)(ws + 92274688);           //  3 MiB  [2][1536][512]
    u16*   WpT = (u16*)(ws + 95420416);           //  1 MiB  [2][512][512]
    float* pe  = (float*)(ws + 96468992);         //  2 MiB  [1024][512]
    u16*   S   = kT;                              // S/att alias (kT dead after K2)

    k_xbf<<<8192, 256, 0, stream>>>(x, xbf);
    k_pe<<<2048, 256, 0, stream>>>(pe);
    for (int hh = 0; hh < 2; ++hh) {
        const int h = hh ? 3 : 0;   // heads 1,2 provably do not affect the output
        k_tr<<<dim3(48, 16), 256, 0, stream>>>(Wqkv + (size_t)h * 786432, WqT + (size_t)hh * 786432, 512, 1536);
        k_tr<<<dim3(16, 16), 256, 0, stream>>>(Wp   + (size_t)h * 262144, WpT + (size_t)hh * 262144, 512, 512);
    }
    for (int p = 0; p < 2; ++p) {
        const int h = p ? 3 : 0;
        for (int ck = 0; ck < 2; ++ck) {
            const u16* xc = xbf + (size_t)ck * 16384 * 512;
            k1_qkv<<<dim3(12, 128), 256, 0, stream>>>(xc, WqT + (size_t)p * 786432,
                                                      bqkv + (size_t)h * 1536, q, kT, vT);
            k2_ktv<<<dim3(4, 4, 16), 256, 0, stream>>>(kT, vT, Mt);
            k3a_s<<<dim3(4, 128), 256, 0, stream>>>(q, Mt, S);
            k3b_sm<<<4096, 256, 0, stream>>>(S);
            k3c_proj<<<dim3(4, 128), 256, 0, stream>>>(S, WpT + (size_t)p * 262144,
                                                       bp + (size_t)h * 512, pe, out, p, ck * 16384);
        }
    }
}